// Round 1
// baseline (554.779 us; speedup 1.0000x reference)
//
#include <hip/hip_runtime.h>

// GCN 2-layer + linear head on MI355X.
// x[N,26] f32, edge_index[2,E] int32, W1[26,64], b1[64], W2[64,32], b2[32], Wl[32,1], bl[1]
// out[N,1] f32.

#define TPB 256

__global__ void init_deg_kernel(float* deg, int n) {
    int i = blockIdx.x * TPB + threadIdx.x;
    if (i < n) deg[i] = 1.0f;  // self-loop contributes 1
}

__global__ void count_deg_kernel(const int* __restrict__ dst, float* deg, int e) {
    int i = blockIdx.x * TPB + threadIdx.x;
    if (i < e) atomicAdd(&deg[dst[i]], 1.0f);
}

__global__ void rsqrt_deg_kernel(float* deg, int n) {
    int i = blockIdx.x * TPB + threadIdx.x;
    if (i < n) deg[i] = rsqrtf(deg[i]);  // deg >= 1 always (self-loop)
}

// xw = x[N,26] @ W[26,64]
__global__ void gemm_xw1_kernel(const float* __restrict__ x, const float* __restrict__ W,
                                float* __restrict__ out, int n) {
    __shared__ float sW[26 * 64];
    __shared__ float sx[4][26];
    int t = threadIdx.x;
    for (int i = t; i < 26 * 64; i += TPB) sW[i] = W[i];
    int node0 = blockIdx.x * 4;
    if (t < 4 * 26) {
        int r = t / 26, c = t % 26;
        int node = node0 + r;
        sx[r][c] = (node < n) ? x[node * 26 + c] : 0.0f;
    }
    __syncthreads();
    int r = t >> 6;      // 0..3
    int f = t & 63;      // 0..63
    int node = node0 + r;
    if (node < n) {
        float acc = 0.0f;
#pragma unroll
        for (int k = 0; k < 26; ++k) acc += sx[r][k] * sW[k * 64 + f];
        out[node * 64 + f] = acc;
    }
}

// xw2 = h[N,64] @ W[64,32]
__global__ void gemm_xw2_kernel(const float* __restrict__ h, const float* __restrict__ W,
                                float* __restrict__ out, int n) {
    __shared__ float sW[64 * 32];
    __shared__ float sh[8][64];
    int t = threadIdx.x;
    for (int i = t; i < 64 * 32; i += TPB) sW[i] = W[i];
    int node0 = blockIdx.x * 8;
    for (int i = t; i < 8 * 64; i += TPB) {
        int r = i >> 6, c = i & 63;
        int node = node0 + r;
        sh[r][c] = (node < n) ? h[node * 64 + c] : 0.0f;
    }
    __syncthreads();
    int r = t >> 5;      // 0..7
    int f = t & 31;      // 0..31
    int node = node0 + r;
    if (node < n) {
        float acc = 0.0f;
#pragma unroll
        for (int k = 0; k < 64; ++k) acc += sh[r][k] * sW[k * 32 + f];
        out[node * 32 + f] = acc;
    }
}

// out[n][f] = dis[n]^2 * xw[n][f]   (self-loop term, also serves as zero-init)
template <int F>
__global__ void self_loop_init_kernel(const float* __restrict__ xw, const float* __restrict__ dis,
                                      float* __restrict__ out, int n) {
    int i = blockIdx.x * TPB + threadIdx.x;
    if (i < n * F) {
        int node = i / F;
        float d = dis[node];
        out[i] = d * d * xw[i];
    }
}

// out[dst][f] += dis[src]*dis[dst] * xw[src][f]  per edge
template <int F>
__global__ void scatter_edges_kernel(const int* __restrict__ srcv, const int* __restrict__ dstv,
                                     const float* __restrict__ dis, const float* __restrict__ xw,
                                     float* out, int e) {
    int i = blockIdx.x * TPB + threadIdx.x;
    if (i >= e * F) return;
    int ed = i / F;
    int f = i % F;
    int s = srcv[ed];
    int d = dstv[ed];
    float norm = dis[s] * dis[d];
    atomicAdd(&out[d * F + f], norm * xw[s * F + f]);
}

template <int F>
__global__ void bias_relu_kernel(float* h, const float* __restrict__ b, int n) {
    int i = blockIdx.x * TPB + threadIdx.x;
    if (i < n * F) {
        float v = h[i] + b[i % F];
        h[i] = v > 0.0f ? v : 0.0f;
    }
}

// out[n] = dot(h[n, 0:32], Wl) + bl
__global__ void final_linear_kernel(const float* __restrict__ h, const float* __restrict__ Wl,
                                    const float* __restrict__ bl, float* __restrict__ out, int n) {
    __shared__ float sW[32];
    if (threadIdx.x < 32) sW[threadIdx.x] = Wl[threadIdx.x];
    __syncthreads();
    int i = blockIdx.x * TPB + threadIdx.x;
    if (i < n) {
        const float4* row = (const float4*)(h + (size_t)i * 32);
        float acc = 0.0f;
#pragma unroll
        for (int k = 0; k < 8; ++k) {
            float4 v = row[k];
            acc += v.x * sW[4 * k] + v.y * sW[4 * k + 1] + v.z * sW[4 * k + 2] + v.w * sW[4 * k + 3];
        }
        out[i] = acc + bl[0];
    }
}

extern "C" void kernel_launch(void* const* d_in, const int* in_sizes, int n_in,
                              void* d_out, int out_size, void* d_ws, size_t ws_size,
                              hipStream_t stream) {
    const float* x  = (const float*)d_in[0];
    const int*   ei = (const int*)d_in[1];
    const float* W1 = (const float*)d_in[2];
    const float* b1 = (const float*)d_in[3];
    const float* W2 = (const float*)d_in[4];
    const float* b2 = (const float*)d_in[5];
    const float* Wl = (const float*)d_in[6];
    const float* bl = (const float*)d_in[7];
    float* out = (float*)d_out;

    const int n = in_sizes[0] / 26;
    const int e = in_sizes[1] / 2;
    const int* src = ei;
    const int* dst = ei + e;

    // workspace layout (floats): dis[n] | bufA[n*64] | bufB[n*64]
    float* ws  = (float*)d_ws;
    float* dis = ws;                 // n
    float* bufA = ws + n;            // n*64 : xw1, later xw2 (first 32n) + h2 (second 32n)
    float* bufB = bufA + (size_t)n * 64;  // n*64 : agg1 -> relu -> h1

    float* xw1 = bufA;
    float* h1  = bufB;
    float* xw2 = bufA;                       // first 32n floats
    float* h2  = bufA + (size_t)n * 32;      // second 32n floats

    int gb_n   = (n + TPB - 1) / TPB;
    int gb_e   = (e + TPB - 1) / TPB;

    // 1) degrees (in-degree + 1) -> rsqrt
    init_deg_kernel<<<gb_n, TPB, 0, stream>>>(dis, n);
    count_deg_kernel<<<gb_e, TPB, 0, stream>>>(dst, dis, e);
    rsqrt_deg_kernel<<<gb_n, TPB, 0, stream>>>(dis, n);

    // 2) layer 1: xw1 = x @ W1
    gemm_xw1_kernel<<<(n + 3) / 4, TPB, 0, stream>>>(x, W1, xw1, n);

    // 3) aggregate: h1 = D^-1/2 (A+I) D^-1/2 xw1
    self_loop_init_kernel<64><<<((size_t)n * 64 + TPB - 1) / TPB, TPB, 0, stream>>>(xw1, dis, h1, n);
    scatter_edges_kernel<64><<<((size_t)e * 64 + TPB - 1) / TPB, TPB, 0, stream>>>(src, dst, dis, xw1, h1, e);
    bias_relu_kernel<64><<<((size_t)n * 64 + TPB - 1) / TPB, TPB, 0, stream>>>(h1, b1, n);

    // 4) layer 2: xw2 = h1 @ W2
    gemm_xw2_kernel<<<(n + 7) / 8, TPB, 0, stream>>>(h1, W2, xw2, n);

    // 5) aggregate: h2 = D^-1/2 (A+I) D^-1/2 xw2
    self_loop_init_kernel<32><<<((size_t)n * 32 + TPB - 1) / TPB, TPB, 0, stream>>>(xw2, dis, h2, n);
    scatter_edges_kernel<32><<<((size_t)e * 32 + TPB - 1) / TPB, TPB, 0, stream>>>(src, dst, dis, xw2, h2, e);
    bias_relu_kernel<32><<<((size_t)n * 32 + TPB - 1) / TPB, TPB, 0, stream>>>(h2, b2, n);

    // 6) head: out = h2 @ Wl + bl
    final_linear_kernel<<<gb_n, TPB, 0, stream>>>(h2, Wl, bl, out, n);
}

// Round 2
// 349.803 us; speedup vs baseline: 1.5860x; 1.5860x over previous
//
#include <hip/hip_runtime.h>

// GCN 2-layer + linear head on MI355X — CSR-gather formulation (no float atomics).
// x[N,26] f32, edge_index[2,E] int32, W1[26,64], b1[64], W2[64,32], b2[32], Wl[32,1], bl[1]
// out[N,1] f32.
//
// Math: out = relu(agg(relu(agg(X)@W1 + b1)@W2) + b2) @ Wl + bl
// where agg(Y) = D^-1/2 (A+I) D^-1/2 Y  (aggregation is linear, so it commutes
// with the dense transform; layer 1 aggregates X [26 feats] instead of X@W1 [64]).

#define TPB 256

__global__ void zero_cnt_kernel(int* cnt, int n) {
    int i = blockIdx.x * TPB + threadIdx.x;
    if (i < n) cnt[i] = 0;
}

__global__ void hist_kernel(const int* __restrict__ dst, int* cnt, int e) {
    int i = blockIdx.x * TPB + threadIdx.x;
    if (i < e) atomicAdd(&cnt[dst[i]], 1);
}

__global__ void dis_kernel(const int* __restrict__ cnt, float* dis, int n) {
    int i = blockIdx.x * TPB + threadIdx.x;
    if (i < n) dis[i] = rsqrtf((float)cnt[i] + 1.0f);  // +1 self-loop
}

// per-block exclusive scan of cnt -> offs, block sums -> bsum
__global__ void scan_block_kernel(const int* __restrict__ cnt, int* offs, int* bsum, int n) {
    __shared__ int s[TPB];
    int i = blockIdx.x * TPB + threadIdx.x;
    int v = (i < n) ? cnt[i] : 0;
    s[threadIdx.x] = v;
    __syncthreads();
#pragma unroll
    for (int d = 1; d < TPB; d <<= 1) {
        int t = (threadIdx.x >= d) ? s[threadIdx.x - d] : 0;
        __syncthreads();
        s[threadIdx.x] += t;
        __syncthreads();
    }
    if (i < n) offs[i] = s[threadIdx.x] - v;  // exclusive
    if (threadIdx.x == TPB - 1) bsum[blockIdx.x] = s[TPB - 1];
}

__global__ void scan_bsum_kernel(int* bsum, int nb) {
    if (blockIdx.x == 0 && threadIdx.x == 0) {
        int a = 0;
        for (int i = 0; i < nb; ++i) { int t = bsum[i]; bsum[i] = a; a += t; }
    }
}

__global__ void add_offs_kernel(int* offs, int* ptr, const int* __restrict__ bsum, int n, int e) {
    int i = blockIdx.x * TPB + threadIdx.x;
    if (i < n) {
        int o = offs[i] + bsum[i >> 8];
        offs[i] = o;
        ptr[i] = o;
    }
    if (i == 0) offs[n] = e;
}

__global__ void fill_kernel(const int* __restrict__ srcv, const int* __restrict__ dstv,
                            const float* __restrict__ dis, int* ptr,
                            int* slot_src, float* slot_norm, int e) {
    int i = blockIdx.x * TPB + threadIdx.x;
    if (i >= e) return;
    int s = srcv[i];
    int d = dstv[i];
    int pos = atomicAdd(&ptr[d], 1);
    slot_src[pos] = s;
    slot_norm[pos] = dis[s] * dis[d];
}

// ax[node][f] = dis^2 * x[node][f] + sum_edges norm * x[src][f]   (F=26, 32 lanes/node)
__global__ void gather1_kernel(const float* __restrict__ x, const float* __restrict__ dis,
                               const int* __restrict__ offs, const int* __restrict__ slot_src,
                               const float* __restrict__ slot_norm,
                               float* __restrict__ ax, int n) {
    int sub = threadIdx.x >> 5;
    int f = threadIdx.x & 31;
    int node = blockIdx.x * 8 + sub;
    if (node >= n || f >= 26) return;
    float di = dis[node];
    float acc = di * di * x[node * 26 + f];
    int j = offs[node], end = offs[node + 1];
    for (; j + 1 < end; j += 2) {
        int s0 = slot_src[j];     float w0 = slot_norm[j];
        int s1 = slot_src[j + 1]; float w1 = slot_norm[j + 1];
        float v0 = x[s0 * 26 + f];
        float v1 = x[s1 * 26 + f];
        acc += w0 * v0;
        acc += w1 * v1;
    }
    if (j < end) acc += slot_norm[j] * x[slot_src[j] * 26 + f];
    ax[node * 26 + f] = acc;
}

// h1 = relu(ax[N,26] @ W1[26,64] + b1)
__global__ void gemm1_kernel(const float* __restrict__ ax, const float* __restrict__ W,
                             const float* __restrict__ b, float* __restrict__ out, int n) {
    __shared__ float sW[26 * 64];
    __shared__ float sx[4][26];
    int t = threadIdx.x;
    for (int i = t; i < 26 * 64; i += TPB) sW[i] = W[i];
    int node0 = blockIdx.x * 4;
    if (t < 4 * 26) {
        int r = t / 26, c = t % 26;
        int node = node0 + r;
        sx[r][c] = (node < n) ? ax[node * 26 + c] : 0.0f;
    }
    __syncthreads();
    int r = t >> 6;      // 0..3
    int f = t & 63;      // 0..63
    int node = node0 + r;
    if (node < n) {
        float acc = b[f];
#pragma unroll
        for (int k = 0; k < 26; ++k) acc += sx[r][k] * sW[k * 64 + f];
        out[node * 64 + f] = acc > 0.0f ? acc : 0.0f;
    }
}

// xw2 = h1[N,64] @ W2[64,32]   (bias applied after aggregation)
__global__ void gemm2_kernel(const float* __restrict__ h, const float* __restrict__ W,
                             float* __restrict__ out, int n) {
    __shared__ float sW[64 * 32];
    __shared__ float sh[8][64];
    int t = threadIdx.x;
    for (int i = t; i < 64 * 32; i += TPB) sW[i] = W[i];
    int node0 = blockIdx.x * 8;
    for (int i = t; i < 8 * 64; i += TPB) {
        int r = i >> 6, c = i & 63;
        int node = node0 + r;
        sh[r][c] = (node < n) ? h[node * 64 + c] : 0.0f;
    }
    __syncthreads();
    int r = t >> 5;      // 0..7
    int f = t & 31;      // 0..31
    int node = node0 + r;
    if (node < n) {
        float acc = 0.0f;
#pragma unroll
        for (int k = 0; k < 64; ++k) acc += sh[r][k] * sW[k * 32 + f];
        out[node * 32 + f] = acc;
    }
}

// fused: h2 = relu(agg(xw2) + b2); out[node] = dot(h2_row, Wl) + bl   (F=32, 32 lanes/node)
__global__ void gather2_head_kernel(const float* __restrict__ xw2, const float* __restrict__ dis,
                                    const int* __restrict__ offs, const int* __restrict__ slot_src,
                                    const float* __restrict__ slot_norm,
                                    const float* __restrict__ b2, const float* __restrict__ Wl,
                                    const float* __restrict__ bl,
                                    float* __restrict__ out, int n) {
    int sub = threadIdx.x >> 5;
    int f = threadIdx.x & 31;
    int node = blockIdx.x * 8 + sub;
    if (node >= n) return;
    float di = dis[node];
    float acc = di * di * xw2[node * 32 + f];
    int j = offs[node], end = offs[node + 1];
    for (; j + 1 < end; j += 2) {
        int s0 = slot_src[j];     float w0 = slot_norm[j];
        int s1 = slot_src[j + 1]; float w1 = slot_norm[j + 1];
        float v0 = xw2[s0 * 32 + f];
        float v1 = xw2[s1 * 32 + f];
        acc += w0 * v0;
        acc += w1 * v1;
    }
    if (j < end) acc += slot_norm[j] * xw2[slot_src[j] * 32 + f];
    float v = acc + b2[f];
    v = v > 0.0f ? v : 0.0f;
    float c = v * Wl[f];
#pragma unroll
    for (int m = 16; m >= 1; m >>= 1) c += __shfl_xor(c, m, 32);
    if (f == 0) out[node] = c + bl[0];
}

extern "C" void kernel_launch(void* const* d_in, const int* in_sizes, int n_in,
                              void* d_out, int out_size, void* d_ws, size_t ws_size,
                              hipStream_t stream) {
    const float* x  = (const float*)d_in[0];
    const int*   ei = (const int*)d_in[1];
    const float* W1 = (const float*)d_in[2];
    const float* b1 = (const float*)d_in[3];
    const float* W2 = (const float*)d_in[4];
    const float* b2 = (const float*)d_in[5];
    const float* Wl = (const float*)d_in[6];
    const float* bl = (const float*)d_in[7];
    float* out = (float*)d_out;

    const int n = in_sizes[0] / 26;
    const int e = in_sizes[1] / 2;
    const int* src = ei;
    const int* dst = ei + e;

    const int nb = (n + TPB - 1) / TPB;  // scan blocks

    // workspace layout
    char* p = (char*)d_ws;
    float* dis      = (float*)p;                 p += (size_t)n * 4;
    int*   cnt      = (int*)p;                   p += (size_t)n * 4;
    int*   offs     = (int*)p;                   p += (size_t)(n + 1) * 4;
    int*   ptr      = (int*)p;                   p += (size_t)n * 4;
    int*   bsum     = (int*)p;                   p += (size_t)(nb + 1) * 4;
    int*   slot_src = (int*)p;                   p += (size_t)e * 4;
    float* slot_nrm = (float*)p;                 p += (size_t)e * 4;
    float* bufA     = (float*)p;                 p += (size_t)n * 64 * 4;  // h1
    float* bufB     = (float*)p;                 p += (size_t)n * 32 * 4;  // ax (26n), then xw2 (32n)

    float* ax  = bufB;
    float* h1  = bufA;
    float* xw2 = bufB;

    int gb_n = nb;
    int gb_e = (e + TPB - 1) / TPB;
    int gb_g = (n + 7) / 8;  // gather: 8 nodes/block

    // 1) CSR build
    zero_cnt_kernel<<<gb_n, TPB, 0, stream>>>(cnt, n);
    hist_kernel<<<gb_e, TPB, 0, stream>>>(dst, cnt, e);
    dis_kernel<<<gb_n, TPB, 0, stream>>>(cnt, dis, n);
    scan_block_kernel<<<gb_n, TPB, 0, stream>>>(cnt, offs, bsum, n);
    scan_bsum_kernel<<<1, 64, 0, stream>>>(bsum, nb);
    add_offs_kernel<<<gb_n, TPB, 0, stream>>>(offs, ptr, bsum, n, e);
    fill_kernel<<<gb_e, TPB, 0, stream>>>(src, dst, dis, ptr, slot_src, slot_nrm, e);

    // 2) layer 1: aggregate x (26 feats), then transform
    gather1_kernel<<<gb_g, TPB, 0, stream>>>(x, dis, offs, slot_src, slot_nrm, ax, n);
    gemm1_kernel<<<(n + 3) / 4, TPB, 0, stream>>>(ax, W1, b1, h1, n);

    // 3) layer 2: transform (32 feats), then aggregate + bias + relu + head (fused)
    gemm2_kernel<<<(n + 7) / 8, TPB, 0, stream>>>(h1, W2, xw2, n);
    gather2_head_kernel<<<gb_g, TPB, 0, stream>>>(xw2, dis, offs, slot_src, slot_nrm,
                                                  b2, Wl, bl, out, n);
}

// Round 3
// 225.106 us; speedup vs baseline: 2.4645x; 1.5539x over previous
//
#include <hip/hip_runtime.h>

// GCN 2-layer + linear head on MI355X — CSR-gather, atomic-free fill.
// out = relu(agg(relu(agg(X)@W1 + b1)@W2) + b2) @ Wl + bl
// agg(Y) = D^-1/2 (A+I) D^-1/2 Y; aggregation commutes with the dense transform.
//
// CSR build: hist records per-edge rank (atomicAdd return), block scan + single
// 512-thread scan over block sums -> offs; fill scatters one int2 {src, dis[src]}
// per edge with NO atomics (pos = offs[dst] + rank).

#define TPB 256

__global__ void zero_cnt_kernel(int* cnt, int n) {
    int i = blockIdx.x * TPB + threadIdx.x;
    if (i < n) cnt[i] = 0;
}

// rank[i] = position of edge i among edges with the same dst
__global__ void hist_rank_kernel(const int* __restrict__ dst, int* cnt, int* rank, int e) {
    int i = blockIdx.x * TPB + threadIdx.x;
    if (i < e) rank[i] = atomicAdd(&cnt[dst[i]], 1);
}

// per-block exclusive scan of cnt -> offs, block sums -> bsum; also dis = rsqrt(cnt+1)
__global__ void scan_block_dis_kernel(const int* __restrict__ cnt, int* offs, int* bsum,
                                      float* dis, int n) {
    __shared__ int s[TPB];
    int i = blockIdx.x * TPB + threadIdx.x;
    int v = (i < n) ? cnt[i] : 0;
    s[threadIdx.x] = v;
    __syncthreads();
#pragma unroll
    for (int d = 1; d < TPB; d <<= 1) {
        int t = (threadIdx.x >= d) ? s[threadIdx.x - d] : 0;
        __syncthreads();
        s[threadIdx.x] += t;
        __syncthreads();
    }
    if (i < n) {
        offs[i] = s[threadIdx.x] - v;  // exclusive
        dis[i] = rsqrtf((float)v + 1.0f);
    }
    if (threadIdx.x == TPB - 1) bsum[blockIdx.x] = s[TPB - 1];
}

// exclusive scan of bsum[0..nb), nb <= 512, single block of 512 threads
__global__ void scan_bsum_kernel(int* bsum, int nb) {
    __shared__ int s[512];
    int i = threadIdx.x;
    int v = (i < nb) ? bsum[i] : 0;
    s[i] = v;
    __syncthreads();
#pragma unroll
    for (int d = 1; d < 512; d <<= 1) {
        int t = (i >= d) ? s[i - d] : 0;
        __syncthreads();
        s[i] += t;
        __syncthreads();
    }
    if (i < nb) bsum[i] = s[i] - v;
}

__global__ void add_offs_kernel(int* offs, const int* __restrict__ bsum, int n, int e) {
    int i = blockIdx.x * TPB + threadIdx.x;
    if (i < n) offs[i] += bsum[i >> 8];
    if (i == 0) offs[n] = e;
}

// slot[offs[dst]+rank] = {src, dis[src]}  — no atomics, one 8B scattered store/edge
__global__ void fill_kernel(const int* __restrict__ srcv, const int* __restrict__ dstv,
                            const int* __restrict__ rank, const int* __restrict__ offs,
                            const float* __restrict__ dis, int2* __restrict__ slot, int e) {
    int i = blockIdx.x * TPB + threadIdx.x;
    if (i >= e) return;
    int d = dstv[i];
    int s = srcv[i];
    int pos = offs[d] + rank[i];
    slot[pos] = make_int2(s, __float_as_int(dis[s]));
}

// sum1[node][f] = dis[node]*x[node][f] + sum_edges dis[src]*x[src][f]   (F=26)
__global__ void gather1_kernel(const float* __restrict__ x, const float* __restrict__ dis,
                               const int* __restrict__ offs, const int2* __restrict__ slot,
                               float* __restrict__ sum1, int n) {
    int sub = threadIdx.x >> 5;
    int f = threadIdx.x & 31;
    int node = blockIdx.x * 8 + sub;
    if (node >= n || f >= 26) return;
    float acc = dis[node] * x[(size_t)node * 26 + f];
    int j = offs[node], end = offs[node + 1];
    for (; j + 3 < end; j += 4) {
        int2 e0 = slot[j], e1 = slot[j + 1], e2 = slot[j + 2], e3 = slot[j + 3];
        float v0 = x[(size_t)e0.x * 26 + f];
        float v1 = x[(size_t)e1.x * 26 + f];
        float v2 = x[(size_t)e2.x * 26 + f];
        float v3 = x[(size_t)e3.x * 26 + f];
        acc += __int_as_float(e0.y) * v0 + __int_as_float(e1.y) * v1 +
               __int_as_float(e2.y) * v2 + __int_as_float(e3.y) * v3;
    }
    for (; j < end; ++j) {
        int2 e0 = slot[j];
        acc += __int_as_float(e0.y) * x[(size_t)e0.x * 26 + f];
    }
    sum1[(size_t)node * 26 + f] = acc;
}

// h1 = relu(dis[node]*sum1[N,26] @ W1[26,64] + b1)   (dis scale folded into LDS load)
__global__ void gemm1_kernel(const float* __restrict__ sum1, const float* __restrict__ dis,
                             const float* __restrict__ W, const float* __restrict__ b,
                             float* __restrict__ out, int n) {
    __shared__ float sW[26 * 64];
    __shared__ float sx[4][26];
    int t = threadIdx.x;
    for (int i = t; i < 26 * 64; i += TPB) sW[i] = W[i];
    int node0 = blockIdx.x * 4;
    if (t < 4 * 26) {
        int r = t / 26, c = t % 26;
        int node = node0 + r;
        sx[r][c] = (node < n) ? dis[node] * sum1[(size_t)node * 26 + c] : 0.0f;
    }
    __syncthreads();
    int r = t >> 6;      // 0..3
    int f = t & 63;      // 0..63
    int node = node0 + r;
    if (node < n) {
        float acc = b[f];
#pragma unroll
        for (int k = 0; k < 26; ++k) acc += sx[r][k] * sW[k * 64 + f];
        out[(size_t)node * 64 + f] = fmaxf(acc, 0.0f);
    }
}

// xw2s = dis[node] * (h1[N,64] @ W2[64,32])   (pre-scaled for gather2)
__global__ void gemm2_kernel(const float* __restrict__ h, const float* __restrict__ dis,
                             const float* __restrict__ W, float* __restrict__ out, int n) {
    __shared__ float sW[64 * 32];
    __shared__ float sh[8][64];
    __shared__ float sdis[8];
    int t = threadIdx.x;
    for (int i = t; i < 64 * 32; i += TPB) sW[i] = W[i];
    int node0 = blockIdx.x * 8;
    for (int i = t; i < 8 * 64; i += TPB) {
        int r = i >> 6, c = i & 63;
        int node = node0 + r;
        sh[r][c] = (node < n) ? h[(size_t)node * 64 + c] : 0.0f;
    }
    if (t < 8) {
        int node = node0 + t;
        sdis[t] = (node < n) ? dis[node] : 0.0f;
    }
    __syncthreads();
    int r = t >> 5;      // 0..7
    int f = t & 31;      // 0..31
    int node = node0 + r;
    if (node < n) {
        float acc = 0.0f;
#pragma unroll
        for (int k = 0; k < 64; ++k) acc += sh[r][k] * sW[k * 32 + f];
        out[(size_t)node * 32 + f] = sdis[r] * acc;
    }
}

// fused: h2 = relu(dis[node]*(xw2s[node] + sum_edges xw2s[src]) + b2); out = h2 @ Wl + bl
__global__ void gather2_head_kernel(const float* __restrict__ xw2s, const float* __restrict__ dis,
                                    const int* __restrict__ offs, const int2* __restrict__ slot,
                                    const float* __restrict__ b2, const float* __restrict__ Wl,
                                    const float* __restrict__ bl,
                                    float* __restrict__ out, int n) {
    int sub = threadIdx.x >> 5;
    int f = threadIdx.x & 31;
    int node = blockIdx.x * 8 + sub;
    if (node >= n) return;
    float acc = xw2s[(size_t)node * 32 + f];
    int j = offs[node], end = offs[node + 1];
    for (; j + 3 < end; j += 4) {
        int2 e0 = slot[j], e1 = slot[j + 1], e2 = slot[j + 2], e3 = slot[j + 3];
        acc += xw2s[(size_t)e0.x * 32 + f] + xw2s[(size_t)e1.x * 32 + f] +
               xw2s[(size_t)e2.x * 32 + f] + xw2s[(size_t)e3.x * 32 + f];
    }
    for (; j < end; ++j) acc += xw2s[(size_t)slot[j].x * 32 + f];
    float v = fmaxf(dis[node] * acc + b2[f], 0.0f);
    float c = v * Wl[f];
#pragma unroll
    for (int m = 16; m >= 1; m >>= 1) c += __shfl_xor(c, m, 32);
    if (f == 0) out[node] = c + bl[0];
}

extern "C" void kernel_launch(void* const* d_in, const int* in_sizes, int n_in,
                              void* d_out, int out_size, void* d_ws, size_t ws_size,
                              hipStream_t stream) {
    const float* x  = (const float*)d_in[0];
    const int*   ei = (const int*)d_in[1];
    const float* W1 = (const float*)d_in[2];
    const float* b1 = (const float*)d_in[3];
    const float* W2 = (const float*)d_in[4];
    const float* b2 = (const float*)d_in[5];
    const float* Wl = (const float*)d_in[6];
    const float* bl = (const float*)d_in[7];
    float* out = (float*)d_out;

    const int n = in_sizes[0] / 26;
    const int e = in_sizes[1] / 2;
    const int* src = ei;
    const int* dst = ei + e;

    const int nb = (n + TPB - 1) / TPB;  // scan blocks (must be <= 512)

    // workspace layout, 256B-aligned regions
    auto align_up = [](size_t v) { return (v + 255) & ~(size_t)255; };
    char* p = (char*)d_ws;
    float* dis  = (float*)p;  p += align_up((size_t)n * 4);
    int*   cnt  = (int*)p;    p += align_up((size_t)n * 4);
    int*   offs = (int*)p;    p += align_up((size_t)(n + 1) * 4);
    int*   bsum = (int*)p;    p += align_up(512 * 4);
    // U1 region: rank[e] (hist->fill), then sum1[26n] (gather1->gemm1), then xw2s[32n]
    // (gemm2->gather2) — lifetimes are disjoint.
    char*  U1   = p;          p += align_up((size_t)n * 32 * 4);
    int2*  slot = (int2*)p;   p += align_up((size_t)e * 8);
    float* h1   = (float*)p;  p += align_up((size_t)n * 64 * 4);

    int*   rank = (int*)U1;
    float* sum1 = (float*)U1;
    float* xw2s = (float*)U1;

    int gb_n = nb;
    int gb_e = (e + TPB - 1) / TPB;
    int gb_g = (n + 7) / 8;  // gather: 8 nodes/block

    // 1) CSR build (atomic-free fill)
    zero_cnt_kernel<<<gb_n, TPB, 0, stream>>>(cnt, n);
    hist_rank_kernel<<<gb_e, TPB, 0, stream>>>(dst, cnt, rank, e);
    scan_block_dis_kernel<<<gb_n, TPB, 0, stream>>>(cnt, offs, bsum, dis, n);
    scan_bsum_kernel<<<1, 512, 0, stream>>>(bsum, nb);
    add_offs_kernel<<<gb_n, TPB, 0, stream>>>(offs, bsum, n, e);
    fill_kernel<<<gb_e, TPB, 0, stream>>>(src, dst, rank, offs, dis, slot, e);

    // 2) layer 1: aggregate x (26 feats), then transform (+bias+relu)
    gather1_kernel<<<gb_g, TPB, 0, stream>>>(x, dis, offs, slot, sum1, n);
    gemm1_kernel<<<(n + 3) / 4, TPB, 0, stream>>>(sum1, dis, W1, b1, h1, n);

    // 3) layer 2: transform (pre-scaled), aggregate + bias + relu + head (fused)
    gemm2_kernel<<<(n + 7) / 8, TPB, 0, stream>>>(h1, dis, W2, xw2s, n);
    gather2_head_kernel<<<gb_g, TPB, 0, stream>>>(xw2s, dis, offs, slot, b2, Wl, bl, out, n);
}